// Round 5
// baseline (275.634 us; speedup 1.0000x reference)
//
#include <hip/hip_runtime.h>
#include <hip/hip_bf16.h>
#include <stdint.h>

typedef __bf16 bf16x8 __attribute__((ext_vector_type(8)));
typedef __bf16 bf16x4 __attribute__((ext_vector_type(4)));
typedef float f32x4 __attribute__((ext_vector_type(4)));

#define B_ 2
#define LQ_ 2048
#define LK_ 2048
#define NH_ 16
#define DH_ 64
#define DM_ 1024
#define NKT_ (LK_ / 64)

#define AS1 __attribute__((address_space(1)))
#define AS3 __attribute__((address_space(3)))

__device__ __forceinline__ void gload_lds16(const void* g, void* l) {
  __builtin_amdgcn_global_load_lds((const AS1 uint32_t*)g, (AS3 uint32_t*)l, 16, 0, 0);
}

// Fused prep: blocks [0,960) convert q,k,v,Wq,Wk,Wv fp32 -> bf16 in k-tiled
// layout T[kt][row][32] (chunk c' stores true chunk c'^(row&3) so proj's LDS
// frag reads land conflict-spread); blocks [960,9152) pack the mask to bits.
__global__ __launch_bounds__(256) void prep_kernel(
    const float* __restrict__ q, const float* __restrict__ k,
    const float* __restrict__ v, const float* __restrict__ wq,
    const float* __restrict__ wk, const float* __restrict__ wv,
    const int* __restrict__ mask,
    __bf16* __restrict__ Xt0, __bf16* __restrict__ Xt1, __bf16* __restrict__ Xt2,
    __bf16* __restrict__ Wt0, __bf16* __restrict__ Wt1, __bf16* __restrict__ Wt2,
    unsigned* __restrict__ maskp) {
  const int t = threadIdx.x;
  const int bidx = blockIdx.x;
  if (bidx >= 960) {
    // ---- mask pack: thread covers 4 ints; nibble OR-reduce over 8 lanes ----
    int pb = bidx - 960;
    int lane = t & 63;
    size_t gi = ((size_t)pb * 256 + t) * 4;
    int4 mv = *(const int4*)(mask + gi);
    unsigned nib = (mv.x != 0 ? 1u : 0u) | (mv.y != 0 ? 2u : 0u) |
                   (mv.z != 0 ? 4u : 0u) | (mv.w != 0 ? 8u : 0u);
    unsigned vv = nib << ((lane & 7) * 4);
    vv |= __shfl_xor(vv, 1, 64);
    vv |= __shfl_xor(vv, 2, 64);
    vv |= __shfl_xor(vv, 4, 64);
    if ((lane & 7) == 0) maskp[gi >> 5] = vv;
    return;
  }
  // ---- cvt: 16 source rows x 1024 k through LDS transpose ----
  __shared__ __align__(16) __bf16 lb[16][1032];
  const float* src; __bf16* dst; int rows, m0;
  if (bidx < 256)      { src = q;  dst = Xt0; rows = 4096; m0 = bidx * 16; }
  else if (bidx < 512) { src = k;  dst = Xt1; rows = 4096; m0 = (bidx - 256) * 16; }
  else if (bidx < 768) { src = v;  dst = Xt2; rows = 4096; m0 = (bidx - 512) * 16; }
  else if (bidx < 832) { src = wq; dst = Wt0; rows = 1024; m0 = (bidx - 768) * 16; }
  else if (bidx < 896) { src = wk; dst = Wt1; rows = 1024; m0 = (bidx - 832) * 16; }
  else                 { src = wv; dst = Wt2; rows = 1024; m0 = (bidx - 896) * 16; }
#pragma unroll
  for (int i = 0; i < 16; i++) {
    float4 f = *(const float4*)(src + (size_t)(m0 + i) * DM_ + t * 4);
    bf16x4 o;
    o[0] = (__bf16)f.x; o[1] = (__bf16)f.y; o[2] = (__bf16)f.z; o[3] = (__bf16)f.w;
    *(bf16x4*)&lb[i][t * 4] = o;
  }
  __syncthreads();
  const int wave = t >> 6, lane = t & 63;
  const int m = lane >> 2, c = lane & 3;
#pragma unroll
  for (int j = 0; j < 8; j++) {
    int kt = wave * 8 + j;
    bf16x8 val = *(const bf16x8*)&lb[m][kt * 32 + (c ^ (m & 3)) * 8];
    *(bf16x8*)(dst + ((size_t)kt * rows + m0 + m) * 32 + c * 8) = val;  // 1KB/instr
  }
}

// GEMM C = X @ W^T + bias, 128x128 tile, BK=32, double-buffered staging from
// k-tiled inputs: each global_load_lds covers one contiguous 1KB span.
// mode=blockIdx.z: 0=q(std), 1=k(std+T), 2=v(T). T out: T[bh][kti][d][64].
// mode-0 (qh) output pre-scaled by log2e/8 so attn's exp2 needs no mul.
__global__ __launch_bounds__(256) void proj_kernel(
    const __bf16* __restrict__ Xt0, const __bf16* __restrict__ Xt1,
    const __bf16* __restrict__ Xt2,
    const float* __restrict__ b0p, const float* __restrict__ b1p,
    const float* __restrict__ b2p,
    const __bf16* __restrict__ Wt0, const __bf16* __restrict__ Wt1,
    const __bf16* __restrict__ Wt2,
    __bf16* __restrict__ qh, __bf16* __restrict__ kh,
    __bf16* __restrict__ khT, __bf16* __restrict__ vhT) {
  __shared__ __align__(16) __bf16 smem[2][2][128 * 32];
  __bf16* cbuf = &smem[0][0][0];  // epilogue alias (18 KB < 32 KB)

  const int mode = blockIdx.z;
  const __bf16* Xt = mode == 0 ? Xt0 : (mode == 1 ? Xt1 : Xt2);
  const __bf16* Wt = mode == 0 ? Wt0 : (mode == 1 ? Wt1 : Wt2);
  const float* bias = mode == 0 ? b0p : (mode == 1 ? b1p : b2p);
  __bf16* ostd = mode == 0 ? qh : (mode == 1 ? kh : nullptr);
  __bf16* otr = mode == 0 ? nullptr : (mode == 1 ? khT : vhT);
  const float osc = mode == 0 ? 0.18033688f : 1.0f;  // log2(e)/8 folded into Q

  const int t = threadIdx.x;
  const int wave = t >> 6, lane = t & 63;
  const int lo16 = lane & 15, quad = lane >> 4;
  const int wm = wave >> 1, wn = wave & 1;
  const int m0 = blockIdx.x * 128, n0 = blockIdx.y * 128;

  f32x4 acc[4][4] = {};

  auto stage = [&](int kt, int sel) {
#pragma unroll
    for (int ii = 2 * wave; ii < 2 * wave + 2; ii++) {
      gload_lds16(Xt + ((size_t)kt * 4096 + m0 + ii * 16) * 32 + lane * 8,
                  &smem[sel][0][ii * 512]);
      gload_lds16(Wt + ((size_t)kt * 1024 + n0 + ii * 16) * 32 + lane * 8,
                  &smem[sel][1][ii * 512]);
    }
  };

  stage(0, 0);
  for (int kt = 0; kt < 32; kt++) {
    const int sel = kt & 1;
    __syncthreads();
    if (kt + 1 < 32) stage(kt + 1, sel ^ 1);
    bf16x8 af[4], bfr[4];
#pragma unroll
    for (int g = 0; g < 4; g++) {
      int ar = wm * 64 + g * 16 + lo16;
      af[g] = *(const bf16x8*)(&smem[sel][0][ar * 32 + (quad ^ (ar & 3)) * 8]);
      int br = wn * 64 + g * 16 + lo16;
      bfr[g] = *(const bf16x8*)(&smem[sel][1][br * 32 + (quad ^ (br & 3)) * 8]);
    }
#pragma unroll
    for (int gm = 0; gm < 4; gm++)
#pragma unroll
      for (int gn = 0; gn < 4; gn++)
        acc[gm][gn] =
            __builtin_amdgcn_mfma_f32_16x16x32_bf16(af[gm], bfr[gn], acc[gm][gn], 0, 0, 0);
  }

  const int b = m0 >> 11, l0 = m0 & 2047;
  for (int nhf = 0; nhf < 2; nhf++) {
    int h = (n0 >> 6) + nhf;
    int bh = b * NH_ + h;
    if (ostd) {
      __syncthreads();
      if (wn == nhf) {
#pragma unroll
        for (int gn = 0; gn < 4; gn++) {
          float bi = bias[n0 + nhf * 64 + gn * 16 + lo16];
#pragma unroll
          for (int gm = 0; gm < 4; gm++)
#pragma unroll
            for (int r = 0; r < 4; r++)
              cbuf[(wm * 64 + gm * 16 + quad * 4 + r) * 72 + gn * 16 + lo16] =
                  (__bf16)((acc[gm][gn][r] + bi) * osc);
        }
      }
      __syncthreads();
      int m = t >> 1, coff = (t & 1) * 32;
      __bf16* dst = ostd + ((size_t)bh * LQ_ + l0 + m) * DH_ + coff;
#pragma unroll
      for (int j = 0; j < 4; j++)
        *(bf16x8*)(dst + j * 8) = *(const bf16x8*)&cbuf[m * 72 + coff + j * 8];
    }
    if (otr) {
      __syncthreads();
      if (wn == nhf) {
#pragma unroll
        for (int gn = 0; gn < 4; gn++) {
          float bi = bias[n0 + nhf * 64 + gn * 16 + lo16];
#pragma unroll
          for (int gm = 0; gm < 4; gm++) {
            bf16x4 pk;
#pragma unroll
            for (int r = 0; r < 4; r++) pk[r] = (__bf16)(acc[gm][gn][r] + bi);
            *(bf16x4*)&cbuf[(gn * 16 + lo16) * 136 + wm * 64 + gm * 16 + quad * 4] = pk;
          }
        }
      }
      __syncthreads();
      int d = t >> 2, mc = (t & 3) * 32;
      int kti = (l0 + mc) >> 6, kl = (l0 + mc) & 63;
      __bf16* dst = otr + ((size_t)(bh * NKT_ + kti) * 64 + d) * 64 + kl;
#pragma unroll
      for (int j = 0; j < 4; j++)
        *(bf16x8*)(dst + j * 8) = *(const bf16x8*)&cbuf[d * 136 + mc + j * 8];
    }
  }
}

// Flash attention (R10): k-split wave decomposition. 8 waves = 4 q-slices
// (32 q-rows) x 2 k-halves (32 k each). B-frag ds_reads (kb/bv/bk) scale
// with k-range, so per-block-tile b128 reads drop 208 -> 112 (LDS read pipe
// was ~83% of elapsed at R9's 88us). MFMA/exp work unchanged. P round-trip
// buffer shared per q-slice with disjoint column halves per wave (wave-
// private RAW). Once-per-block cross-half accumulator reduction through the
// dead staging LDS; half-0 waves finalize out_v, half-1 finalize out_k.
// lsum via MFMA-with-ones; Q pre-scaled in proj -> bare exp2.
// LDS = 48K tiles + 18K p_lds = 66KB -> 2 blocks/CU (16 waves/CU).
__global__ __launch_bounds__(512) void attn_kernel(
    const __bf16* __restrict__ qh, const __bf16* __restrict__ kh,
    const __bf16* __restrict__ khT, const __bf16* __restrict__ vhT,
    const unsigned* __restrict__ maskp,
    float* __restrict__ out_k, float* __restrict__ out_v) {
  // tiles[0]=K (std [k][d]), tiles[1]=K^T ([d][k]), tiles[2]=V^T ([d][k])
  __shared__ __align__(16) __bf16 tiles[3][2][64 * 64];
  __shared__ __align__(16) __bf16 p_lds[4][32][72];  // per q-slice P buffer
  float* red = (float*)&tiles[0][0][0];  // epilogue reduction alias (<=48KB)

  const int t = threadIdx.x;
  const int wave = t >> 6, lane = t & 63;
  const int lo16 = lane & 15, quad = lane >> 4;
  const int half = wave & 1;   // k-half owned by this wave
  const int qs = wave >> 1;    // q-slice (32 rows)
  const int bh = blockIdx.x;
  const int b = bh >> 4, h = bh & 15;
  const int q0 = blockIdx.y * 128 + qs * 32;
  const int srow = lane >> 3;
  const int scg = (lane & 7) ^ srow;  // XOR chunk swizzle (store side)
  const int rsw = lo16 & 7;           // read-side row & 7

  bf16x8 a_q0[2], a_q1[2];
#pragma unroll
  for (int g = 0; g < 2; g++) {
    const __bf16* qrow = qh + ((size_t)bh * LQ_ + q0 + g * 16 + lo16) * DH_ + quad * 8;
    a_q0[g] = *(const bf16x8*)(qrow);
    a_q1[g] = *(const bf16x8*)(qrow + 32);
  }

  bf16x8 ones;
#pragma unroll
  for (int j = 0; j < 8; j++) ones[j] = (__bf16)1.0f;

  f32x4 acc_v[2][4] = {};
  f32x4 acc_k[2][4] = {};
  f32x4 acc_l[2] = {};

  const __bf16* khb = kh + (size_t)bh * LK_ * DH_;
  const __bf16* ktb = khT + (size_t)bh * LK_ * DH_;
  const __bf16* vtb = vhT + (size_t)bh * LK_ * DH_;

  const int row_s = wave * 8 + srow;
  auto stage = [&](int kti, int sel) {
    const int tb = kti * 4096;
    gload_lds16(khb + (size_t)(kti * 64 + row_s) * DH_ + scg * 8, &tiles[0][sel][wave * 512]);
    gload_lds16(ktb + tb + row_s * 64 + scg * 8, &tiles[1][sel][wave * 512]);
    gload_lds16(vtb + tb + row_s * 64 + scg * 8, &tiles[2][sel][wave * 512]);
  };

  stage(0, 0);
  for (int kti = 0; kti < NKT_; kti++) {
    const int cur = kti & 1;
    __syncthreads();  // drains stage(cur), issued a full compute-phase ago
    if (kti + 1 < NKT_) stage(kti + 1, cur ^ 1);

    // one mask word per q-row per tile (this wave's 32-k half); early issue
    unsigned mw[2][4];
#pragma unroll
    for (int g = 0; g < 2; g++) {
      const unsigned* mb =
          maskp + ((size_t)b * LQ_ + q0 + g * 16 + quad * 4) * (LK_ / 32) + kti * 2 + half;
#pragma unroll
      for (int r = 0; r < 4; r++) mw[g][r] = mb[r * (LK_ / 32)];
    }

    // ---- S = Q K^T over this wave's k-half (B-frags g-invariant) ----
    f32x4 s[2][2];
#pragma unroll
    for (int kk = 0; kk < 2; kk++) {
      int krow = half * 32 + kk * 16 + lo16;
      bf16x8 kb0 = *(const bf16x8*)(&tiles[0][cur][krow * 64 + ((quad ^ rsw) * 8)]);
      bf16x8 kb1 = *(const bf16x8*)(&tiles[0][cur][krow * 64 + (((quad + 4) ^ rsw) * 8)]);
#pragma unroll
      for (int g = 0; g < 2; g++) {
        f32x4 z = {};
        z = __builtin_amdgcn_mfma_f32_16x16x32_bf16(a_q0[g], kb0, z, 0, 0, 0);
        z = __builtin_amdgcn_mfma_f32_16x16x32_bf16(a_q1[g], kb1, z, 0, 0, 0);
        s[g][kk] = z;
      }
    }

    // ---- mask + exp2 (Q pre-scaled; fixed max) + P store ----
#pragma unroll
    for (int g = 0; g < 2; g++)
#pragma unroll
      for (int kk = 0; kk < 2; kk++) {
        int bitpos = kk * 16 + lo16;
#pragma unroll
        for (int r = 0; r < 4; r++) {
          float pe = __builtin_amdgcn_exp2f(s[g][kk][r]);
          float p = ((mw[g][r] >> bitpos) & 1) ? pe : 0.0f;
          p_lds[qs][g * 16 + quad * 4 + r][half * 32 + kk * 16 + lo16] = (__bf16)p;
        }
      }

    // ---- P -> A-frags (own k-half columns; wave-private RAW) ----
    bf16x8 a_p[2];
#pragma unroll
    for (int g = 0; g < 2; g++)
      a_p[g] = *(const bf16x8*)&p_lds[qs][g * 16 + lo16][half * 32 + quad * 8];

    // ---- O_v += P V, O_k += P K (B-frags g-invariant; one per gg) ----
#pragma unroll
    for (int gg = 0; gg < 4; gg++) {
      int row_d = gg * 16 + lo16;
      int ch = (half * 4 + quad) ^ rsw;
      bf16x8 bv = *(const bf16x8*)(&tiles[2][cur][row_d * 64 + ch * 8]);
      bf16x8 bk = *(const bf16x8*)(&tiles[1][cur][row_d * 64 + ch * 8]);
#pragma unroll
      for (int g = 0; g < 2; g++) {
        acc_v[g][gg] = __builtin_amdgcn_mfma_f32_16x16x32_bf16(a_p[g], bv, acc_v[g][gg], 0, 0, 0);
        acc_k[g][gg] = __builtin_amdgcn_mfma_f32_16x16x32_bf16(a_p[g], bk, acc_k[g][gg], 0, 0, 0);
      }
    }
#pragma unroll
    for (int g = 0; g < 2; g++)
      acc_l[g] = __builtin_amdgcn_mfma_f32_16x16x32_bf16(a_p[g], ones, acc_l[g], 0, 0, 0);
  }

  // ---- cross-k-half reduction via dead staging LDS (partner = half^1) ----
  const int ridx = qs * 64 + lane;  // same for both partners by design
  f32x4* red4 = (f32x4*)red;
  __syncthreads();
  if (half == 1) {  // pass 1: half-1 publishes acc_v + acc_l (40KB)
#pragma unroll
    for (int g = 0; g < 2; g++) {
#pragma unroll
      for (int gg = 0; gg < 4; gg++) red4[ridx * 10 + g * 4 + gg] = acc_v[g][gg];
      red4[ridx * 10 + 8 + g] = acc_l[g];
    }
  }
  __syncthreads();
  if (half == 0) {  // half-0 sums -> owns full V and full l; then publishes
#pragma unroll     //  its partial acc_k + full acc_l to the same slots
    for (int g = 0; g < 2; g++) {
#pragma unroll
      for (int gg = 0; gg < 4; gg++) acc_v[g][gg] += red4[ridx * 10 + g * 4 + gg];
      acc_l[g] += red4[ridx * 10 + 8 + g];
    }
#pragma unroll
    for (int g = 0; g < 2; g++) {
#pragma unroll
      for (int gg = 0; gg < 4; gg++) red4[ridx * 10 + g * 4 + gg] = acc_k[g][gg];
      red4[ridx * 10 + 8 + g] = acc_l[g];
    }
  }
  __syncthreads();
  if (half == 1) {  // half-1 sums k-partials and adopts the full l
#pragma unroll
    for (int g = 0; g < 2; g++) {
#pragma unroll
      for (int gg = 0; gg < 4; gg++) acc_k[g][gg] += red4[ridx * 10 + g * 4 + gg];
      acc_l[g] = red4[ridx * 10 + 8 + g];
    }
  }

  // half-0 stores out_v, half-1 stores out_k (balanced across 8 waves)
  float* outp = half ? out_k : out_v;
#pragma unroll
  for (int g = 0; g < 2; g++) {
    float inv_l[4];
#pragma unroll
    for (int r = 0; r < 4; r++) inv_l[r] = 1.0f / acc_l[g][r];
    size_t obase = ((size_t)b * LQ_ + q0 + g * 16 + quad * 4) * DM_ + h * DH_;
#pragma unroll
    for (int gg = 0; gg < 4; gg++) {
#pragma unroll
      for (int r = 0; r < 4; r++) {
        size_t idx = obase + (size_t)r * DM_ + gg * 16 + lo16;
        outp[idx] = (half ? acc_k[g][gg][r] : acc_v[g][gg][r]) * inv_l[r];
      }
    }
  }
}

extern "C" void kernel_launch(void* const* d_in, const int* in_sizes, int n_in,
                              void* d_out, int out_size, void* d_ws, size_t ws_size,
                              hipStream_t stream) {
  const float* q = (const float*)d_in[0];
  const float* k = (const float*)d_in[1];
  const float* v = (const float*)d_in[2];
  const int* mask = (const int*)d_in[3];
  const float* Wq = (const float*)d_in[4];
  const float* bq = (const float*)d_in[5];
  const float* Wk = (const float*)d_in[6];
  const float* bk = (const float*)d_in[7];
  const float* Wv = (const float*)d_in[8];
  const float* bv = (const float*)d_in[9];
  float* out = (float*)d_out;

  // ws: qh | kh | khTt | vhTt (bf16, 8.4MB ea) | maskp (1MB)
  const size_t HTOT = (size_t)B_ * NH_ * LQ_ * DH_;
  const size_t XTOT = (size_t)B_ * LQ_ * DM_;
  __bf16* qh = (__bf16*)d_ws;
  __bf16* kh = qh + HTOT;
  __bf16* khT = kh + HTOT;
  __bf16* vhT = khT + HTOT;
  unsigned* maskp = (unsigned*)(vhT + HTOT);

  // k-tiled bf16 X/W scratch lives in d_out (dead before attn writes outputs):
  // 3*8.4 + 3*2.1 = 31.5 MB <= 33.5 MB.
  __bf16* Xt0 = (__bf16*)d_out;
  __bf16* Xt1 = Xt0 + XTOT;
  __bf16* Xt2 = Xt1 + XTOT;
  __bf16* Wt0 = Xt2 + XTOT;
  __bf16* Wt1 = Wt0 + (size_t)DM_ * DM_;
  __bf16* Wt2 = Wt1 + (size_t)DM_ * DM_;

  prep_kernel<<<960 + 8192, 256, 0, stream>>>(
      q, k, v, Wq, Wk, Wv, mask, Xt0, Xt1, Xt2, Wt0, Wt1, Wt2, maskp);
  proj_kernel<<<dim3(32, 8, 3), 256, 0, stream>>>(
      Xt0, Xt1, Xt2, bq, bk, bv, Wt0, Wt1, Wt2, qh, kh, khT, vhT);
  attn_kernel<<<dim3(32, 16), 512, 0, stream>>>(qh, kh, khT, vhT, maskp,
                                                out, out + (size_t)B_ * LQ_ * DM_);
}

// Round 6
// 263.780 us; speedup vs baseline: 1.0449x; 1.0449x over previous
//
#include <hip/hip_runtime.h>
#include <hip/hip_bf16.h>
#include <stdint.h>

typedef __bf16 bf16x8 __attribute__((ext_vector_type(8)));
typedef __bf16 bf16x4 __attribute__((ext_vector_type(4)));
typedef float f32x4 __attribute__((ext_vector_type(4)));

#define B_ 2
#define LQ_ 2048
#define LK_ 2048
#define NH_ 16
#define DH_ 64
#define DM_ 1024
#define NKT_ (LK_ / 64)

#define AS1 __attribute__((address_space(1)))
#define AS3 __attribute__((address_space(3)))

__device__ __forceinline__ void gload_lds16(const void* g, void* l) {
  __builtin_amdgcn_global_load_lds((const AS1 uint32_t*)g, (AS3 uint32_t*)l, 16, 0, 0);
}

// prep (R11): cvt only — q,k,v,Wq,Wk,Wv fp32 -> bf16 k-tiled T[kt][row][32]
// (chunk c' stores true chunk c'^(row&3)). Mask pack moved into proj z==3.
__global__ __launch_bounds__(256) void prep_kernel(
    const float* __restrict__ q, const float* __restrict__ k,
    const float* __restrict__ v, const float* __restrict__ wq,
    const float* __restrict__ wk, const float* __restrict__ wv,
    __bf16* __restrict__ Xt0, __bf16* __restrict__ Xt1, __bf16* __restrict__ Xt2,
    __bf16* __restrict__ Wt0, __bf16* __restrict__ Wt1, __bf16* __restrict__ Wt2) {
  const int t = threadIdx.x;
  const int bidx = blockIdx.x;
  __shared__ __align__(16) __bf16 lb[16][1032];
  const float* src; __bf16* dst; int rows, m0;
  if (bidx < 256)      { src = q;  dst = Xt0; rows = 4096; m0 = bidx * 16; }
  else if (bidx < 512) { src = k;  dst = Xt1; rows = 4096; m0 = (bidx - 256) * 16; }
  else if (bidx < 768) { src = v;  dst = Xt2; rows = 4096; m0 = (bidx - 512) * 16; }
  else if (bidx < 832) { src = wq; dst = Wt0; rows = 1024; m0 = (bidx - 768) * 16; }
  else if (bidx < 896) { src = wk; dst = Wt1; rows = 1024; m0 = (bidx - 832) * 16; }
  else                 { src = wv; dst = Wt2; rows = 1024; m0 = (bidx - 896) * 16; }
#pragma unroll
  for (int i = 0; i < 16; i++) {
    float4 f = *(const float4*)(src + (size_t)(m0 + i) * DM_ + t * 4);
    bf16x4 o;
    o[0] = (__bf16)f.x; o[1] = (__bf16)f.y; o[2] = (__bf16)f.z; o[3] = (__bf16)f.w;
    *(bf16x4*)&lb[i][t * 4] = o;
  }
  __syncthreads();
  const int wave = t >> 6, lane = t & 63;
  const int m = lane >> 2, c = lane & 3;
#pragma unroll
  for (int j = 0; j < 8; j++) {
    int kt = wave * 8 + j;
    bf16x8 val = *(const bf16x8*)&lb[m][kt * 32 + (c ^ (m & 3)) * 8];
    *(bf16x8*)(dst + ((size_t)kt * rows + m0 + m) * 32 + c * 8) = val;  // 1KB/instr
  }
}

// GEMM C = X @ W^T + bias (modes z=0..2) + mask-pack slice (z==3; 256 blocks,
// memory-bound, overlaps the compute-bound GEMM blocks on the same device).
// mode-0 (qh) output pre-scaled by log2e/8 so attn's exp2 needs no mul.
__global__ __launch_bounds__(256) void proj_kernel(
    const __bf16* __restrict__ Xt0, const __bf16* __restrict__ Xt1,
    const __bf16* __restrict__ Xt2,
    const float* __restrict__ b0p, const float* __restrict__ b1p,
    const float* __restrict__ b2p,
    const __bf16* __restrict__ Wt0, const __bf16* __restrict__ Wt1,
    const __bf16* __restrict__ Wt2,
    __bf16* __restrict__ qh, __bf16* __restrict__ kh,
    __bf16* __restrict__ khT, __bf16* __restrict__ vhT,
    const int* __restrict__ mask, unsigned* __restrict__ maskp) {
  const int mode = blockIdx.z;
  const int t = threadIdx.x;
  if (mode == 3) {
    // ---- mask pack: 256 blocks x 32 units; unit = 256 thr x 4 ints ----
    int pb2 = blockIdx.x * 8 + blockIdx.y;
    int lane = t & 63;
#pragma unroll 4
    for (int j = 0; j < 32; j++) {
      int pb = pb2 + 256 * j;
      size_t gi = ((size_t)pb * 256 + t) * 4;
      int4 mv = *(const int4*)(mask + gi);
      unsigned nib = (mv.x != 0 ? 1u : 0u) | (mv.y != 0 ? 2u : 0u) |
                     (mv.z != 0 ? 4u : 0u) | (mv.w != 0 ? 8u : 0u);
      unsigned vv = nib << ((lane & 7) * 4);
      vv |= __shfl_xor(vv, 1, 64);
      vv |= __shfl_xor(vv, 2, 64);
      vv |= __shfl_xor(vv, 4, 64);
      if ((lane & 7) == 0) maskp[gi >> 5] = vv;
    }
    return;
  }
  __shared__ __align__(16) __bf16 smem[2][2][128 * 32];
  __bf16* cbuf = &smem[0][0][0];  // epilogue alias (18 KB < 32 KB)

  const __bf16* Xt = mode == 0 ? Xt0 : (mode == 1 ? Xt1 : Xt2);
  const __bf16* Wt = mode == 0 ? Wt0 : (mode == 1 ? Wt1 : Wt2);
  const float* bias = mode == 0 ? b0p : (mode == 1 ? b1p : b2p);
  __bf16* ostd = mode == 0 ? qh : (mode == 1 ? kh : nullptr);
  __bf16* otr = mode == 0 ? nullptr : (mode == 1 ? khT : vhT);
  const float osc = mode == 0 ? 0.18033688f : 1.0f;  // log2(e)/8 folded into Q

  const int wave = t >> 6, lane = t & 63;
  const int lo16 = lane & 15, quad = lane >> 4;
  const int wm = wave >> 1, wn = wave & 1;
  const int m0 = blockIdx.x * 128, n0 = blockIdx.y * 128;

  f32x4 acc[4][4] = {};

  auto stage = [&](int kt, int sel) {
#pragma unroll
    for (int ii = 2 * wave; ii < 2 * wave + 2; ii++) {
      gload_lds16(Xt + ((size_t)kt * 4096 + m0 + ii * 16) * 32 + lane * 8,
                  &smem[sel][0][ii * 512]);
      gload_lds16(Wt + ((size_t)kt * 1024 + n0 + ii * 16) * 32 + lane * 8,
                  &smem[sel][1][ii * 512]);
    }
  };

  stage(0, 0);
  for (int kt = 0; kt < 32; kt++) {
    const int sel = kt & 1;
    __syncthreads();
    if (kt + 1 < 32) stage(kt + 1, sel ^ 1);
    bf16x8 af[4], bfr[4];
#pragma unroll
    for (int g = 0; g < 4; g++) {
      int ar = wm * 64 + g * 16 + lo16;
      af[g] = *(const bf16x8*)(&smem[sel][0][ar * 32 + (quad ^ (ar & 3)) * 8]);
      int br = wn * 64 + g * 16 + lo16;
      bfr[g] = *(const bf16x8*)(&smem[sel][1][br * 32 + (quad ^ (br & 3)) * 8]);
    }
#pragma unroll
    for (int gm = 0; gm < 4; gm++)
#pragma unroll
      for (int gn = 0; gn < 4; gn++)
        acc[gm][gn] =
            __builtin_amdgcn_mfma_f32_16x16x32_bf16(af[gm], bfr[gn], acc[gm][gn], 0, 0, 0);
  }

  const int b = m0 >> 11, l0 = m0 & 2047;
  for (int nhf = 0; nhf < 2; nhf++) {
    int h = (n0 >> 6) + nhf;
    int bh = b * NH_ + h;
    if (ostd) {
      __syncthreads();
      if (wn == nhf) {
#pragma unroll
        for (int gn = 0; gn < 4; gn++) {
          float bi = bias[n0 + nhf * 64 + gn * 16 + lo16];
#pragma unroll
          for (int gm = 0; gm < 4; gm++)
#pragma unroll
            for (int r = 0; r < 4; r++)
              cbuf[(wm * 64 + gm * 16 + quad * 4 + r) * 72 + gn * 16 + lo16] =
                  (__bf16)((acc[gm][gn][r] + bi) * osc);
        }
      }
      __syncthreads();
      int m = t >> 1, coff = (t & 1) * 32;
      __bf16* dst = ostd + ((size_t)bh * LQ_ + l0 + m) * DH_ + coff;
#pragma unroll
      for (int j = 0; j < 4; j++)
        *(bf16x8*)(dst + j * 8) = *(const bf16x8*)&cbuf[m * 72 + coff + j * 8];
    }
    if (otr) {
      __syncthreads();
      if (wn == nhf) {
#pragma unroll
        for (int gn = 0; gn < 4; gn++) {
          float bi = bias[n0 + nhf * 64 + gn * 16 + lo16];
#pragma unroll
          for (int gm = 0; gm < 4; gm++) {
            bf16x4 pk;
#pragma unroll
            for (int r = 0; r < 4; r++) pk[r] = (__bf16)(acc[gm][gn][r] + bi);
            *(bf16x4*)&cbuf[(gn * 16 + lo16) * 136 + wm * 64 + gm * 16 + quad * 4] = pk;
          }
        }
      }
      __syncthreads();
      int d = t >> 2, mc = (t & 3) * 32;
      int kti = (l0 + mc) >> 6, kl = (l0 + mc) & 63;
      __bf16* dst = otr + ((size_t)(bh * NKT_ + kti) * 64 + d) * 64 + kl;
#pragma unroll
      for (int j = 0; j < 4; j++)
        *(bf16x8*)(dst + j * 8) = *(const bf16x8*)&cbuf[d * 136 + mc + j * 8];
    }
  }
}

// Flash attention (R11 = R9, verified 88.4us, + s_setprio around MFMA
// clusters — T5, +4-7% on attn with phase-diverse co-resident blocks).
// 8 waves x 16 q-rows (512 thr) -> 2 blocks/CU, 16 waves/CU. LDS-staged
// K/KT/VT double-buffered; scalar P LDS round-trip [16][72]; lsum via
// MFMA-with-ones; Q pre-scaled in proj -> bare exp2. LDS = 66 KB.
__global__ __launch_bounds__(512) void attn_kernel(
    const __bf16* __restrict__ qh, const __bf16* __restrict__ kh,
    const __bf16* __restrict__ khT, const __bf16* __restrict__ vhT,
    const unsigned* __restrict__ maskp,
    float* __restrict__ out_k, float* __restrict__ out_v) {
  __shared__ __align__(16) __bf16 kbuf[2][64 * 64];
  __shared__ __align__(16) __bf16 ktbuf[2][64 * 64];
  __shared__ __align__(16) __bf16 vtbuf[2][64 * 64];
  __shared__ __align__(16) __bf16 p_lds[8][16][72];  // per-wave C->A round-trip

  const int t = threadIdx.x;
  const int wave = t >> 6, lane = t & 63;
  const int lo16 = lane & 15, quad = lane >> 4;
  const int bh = blockIdx.x;
  const int b = bh >> 4, h = bh & 15;
  const int q0 = blockIdx.y * 128 + wave * 16;
  const int srow = lane >> 3;
  const int scg = (lane & 7) ^ srow;  // XOR chunk swizzle (store side)
  const int rsw = lo16 & 7;           // read-side row & 7

  bf16x8 a_q0, a_q1;
  {
    const __bf16* qrow = qh + ((size_t)bh * LQ_ + q0 + lo16) * DH_ + quad * 8;
    a_q0 = *(const bf16x8*)(qrow);
    a_q1 = *(const bf16x8*)(qrow + 32);
  }

  bf16x8 ones;
#pragma unroll
  for (int j = 0; j < 8; j++) ones[j] = (__bf16)1.0f;

  f32x4 acc_v[4] = {};
  f32x4 acc_k[4] = {};
  f32x4 acc_l = {};

  const __bf16* khb = kh + (size_t)bh * LK_ * DH_;
  const __bf16* ktb = khT + (size_t)bh * LK_ * DH_;
  const __bf16* vtb = vhT + (size_t)bh * LK_ * DH_;

  const int row_s = wave * 8 + srow;
  auto stage = [&](int kti, int sel) {
    const int tb = kti * 4096;
    gload_lds16(khb + (size_t)(kti * 64 + row_s) * DH_ + scg * 8, &kbuf[sel][wave * 512]);
    gload_lds16(ktb + tb + row_s * 64 + scg * 8, &ktbuf[sel][wave * 512]);
    gload_lds16(vtb + tb + row_s * 64 + scg * 8, &vtbuf[sel][wave * 512]);
  };

  stage(0, 0);
  for (int kti = 0; kti < NKT_; kti++) {
    const int cur = kti & 1;
    __syncthreads();  // drains stage(cur), issued a full compute-phase ago
    if (kti + 1 < NKT_) stage(kti + 1, cur ^ 1);

    // mask words early so VMEM latency hides under QK MFMAs
    const unsigned* mb =
        maskp + ((size_t)b * LQ_ + q0 + quad * 4) * (LK_ / 32) + kti * 2;
    unsigned mw0[4], mw1[4];
#pragma unroll
    for (int r = 0; r < 4; r++) {
      mw0[r] = mb[r * (LK_ / 32)];
      mw1[r] = mb[r * (LK_ / 32) + 1];
    }

    // ---- S = Q K^T ----
    __builtin_amdgcn_s_setprio(1);
    f32x4 s[4];
#pragma unroll
    for (int gg = 0; gg < 4; gg++) {
      int row = gg * 16 + lo16;
      bf16x8 kb0 = *(const bf16x8*)(&kbuf[cur][row * 64 + ((quad ^ rsw) * 8)]);
      bf16x8 kb1 = *(const bf16x8*)(&kbuf[cur][row * 64 + (((quad + 4) ^ rsw) * 8)]);
      f32x4 z = {};
      z = __builtin_amdgcn_mfma_f32_16x16x32_bf16(a_q0, kb0, z, 0, 0, 0);
      z = __builtin_amdgcn_mfma_f32_16x16x32_bf16(a_q1, kb1, z, 0, 0, 0);
      s[gg] = z;
    }
    __builtin_amdgcn_s_setprio(0);

    // ---- mask + exp2 (Q pre-scaled; fixed max) ----
#pragma unroll
    for (int gg = 0; gg < 4; gg++) {
      int bitpos = (gg * 16 + lo16) & 31;
#pragma unroll
      for (int r = 0; r < 4; r++) {
        unsigned w = (gg >= 2) ? mw1[r] : mw0[r];
        float pe = __builtin_amdgcn_exp2f(s[gg][r]);
        s[gg][r] = ((w >> bitpos) & 1) ? pe : 0.0f;
      }
    }

    // ---- P: C-layout regs -> LDS -> A-layout frags (wave-private) ----
#pragma unroll
    for (int gg = 0; gg < 4; gg++)
#pragma unroll
      for (int r = 0; r < 4; r++)
        p_lds[wave][quad * 4 + r][gg * 16 + lo16] = (__bf16)s[gg][r];
    bf16x8 a_p0 = *(const bf16x8*)&p_lds[wave][lo16][quad * 8];
    bf16x8 a_p1 = *(const bf16x8*)&p_lds[wave][lo16][32 + quad * 8];

    // ---- O_v += P V, O_k += P K, lsum += P 1 ----
    __builtin_amdgcn_s_setprio(1);
#pragma unroll
    for (int gg = 0; gg < 4; gg++) {
      int row = gg * 16 + lo16;
      bf16x8 bv0 = *(const bf16x8*)(&vtbuf[cur][row * 64 + ((quad ^ rsw) * 8)]);
      bf16x8 bv1 = *(const bf16x8*)(&vtbuf[cur][row * 64 + (((quad + 4) ^ rsw) * 8)]);
      bf16x8 bk0 = *(const bf16x8*)(&ktbuf[cur][row * 64 + ((quad ^ rsw) * 8)]);
      bf16x8 bk1 = *(const bf16x8*)(&ktbuf[cur][row * 64 + (((quad + 4) ^ rsw) * 8)]);
      acc_v[gg] = __builtin_amdgcn_mfma_f32_16x16x32_bf16(a_p0, bv0, acc_v[gg], 0, 0, 0);
      acc_v[gg] = __builtin_amdgcn_mfma_f32_16x16x32_bf16(a_p1, bv1, acc_v[gg], 0, 0, 0);
      acc_k[gg] = __builtin_amdgcn_mfma_f32_16x16x32_bf16(a_p0, bk0, acc_k[gg], 0, 0, 0);
      acc_k[gg] = __builtin_amdgcn_mfma_f32_16x16x32_bf16(a_p1, bk1, acc_k[gg], 0, 0, 0);
    }
    acc_l = __builtin_amdgcn_mfma_f32_16x16x32_bf16(a_p0, ones, acc_l, 0, 0, 0);
    acc_l = __builtin_amdgcn_mfma_f32_16x16x32_bf16(a_p1, ones, acc_l, 0, 0, 0);
    __builtin_amdgcn_s_setprio(0);
  }

  // acc_l: every column equals the row-sum -> per-reg reciprocal, no shuffle
  float inv_l[4];
#pragma unroll
  for (int r = 0; r < 4; r++) inv_l[r] = 1.0f / acc_l[r];
  size_t obase = ((size_t)b * LQ_ + q0 + quad * 4) * DM_ + h * DH_;
#pragma unroll
  for (int gg = 0; gg < 4; gg++) {
#pragma unroll
    for (int r = 0; r < 4; r++) {
      size_t idx = obase + (size_t)r * DM_ + gg * 16 + lo16;
      out_k[idx] = acc_k[gg][r] * inv_l[r];
      out_v[idx] = acc_v[gg][r] * inv_l[r];
    }
  }
}

extern "C" void kernel_launch(void* const* d_in, const int* in_sizes, int n_in,
                              void* d_out, int out_size, void* d_ws, size_t ws_size,
                              hipStream_t stream) {
  const float* q = (const float*)d_in[0];
  const float* k = (const float*)d_in[1];
  const float* v = (const float*)d_in[2];
  const int* mask = (const int*)d_in[3];
  const float* Wq = (const float*)d_in[4];
  const float* bq = (const float*)d_in[5];
  const float* Wk = (const float*)d_in[6];
  const float* bk = (const float*)d_in[7];
  const float* Wv = (const float*)d_in[8];
  const float* bv = (const float*)d_in[9];
  float* out = (float*)d_out;

  // ws: qh | kh | khT | vhT (bf16, 8.4MB ea) | maskp (1MB) | [scratch if fits]
  const size_t HTOT = (size_t)B_ * NH_ * LQ_ * DH_;
  const size_t XTOT = (size_t)B_ * LQ_ * DM_;
  const size_t MASKW = (size_t)B_ * LQ_ * (LK_ / 32);
  __bf16* qh = (__bf16*)d_ws;
  __bf16* kh = qh + HTOT;
  __bf16* khT = kh + HTOT;
  __bf16* vhT = khT + HTOT;
  unsigned* maskp = (unsigned*)(vhT + HTOT);

  // k-tiled bf16 X/W scratch (31.5 MB): prefer tail of d_ws (avoids the
  // harness re-poisoning d_out between iterations); fall back to d_out
  // (dead until attn writes outputs) when ws is too small.
  const size_t SCR_ELEMS = 3 * XTOT + 3 * (size_t)DM_ * DM_;
  const size_t NEED = 4 * HTOT * sizeof(__bf16) + MASKW * sizeof(unsigned) +
                      SCR_ELEMS * sizeof(__bf16);
  __bf16* scr = (ws_size >= NEED) ? (__bf16*)(maskp + MASKW) : (__bf16*)d_out;
  __bf16* Xt0 = scr;
  __bf16* Xt1 = Xt0 + XTOT;
  __bf16* Xt2 = Xt1 + XTOT;
  __bf16* Wt0 = Xt2 + XTOT;
  __bf16* Wt1 = Wt0 + (size_t)DM_ * DM_;
  __bf16* Wt2 = Wt1 + (size_t)DM_ * DM_;

  prep_kernel<<<960, 256, 0, stream>>>(
      q, k, v, Wq, Wk, Wv, Xt0, Xt1, Xt2, Wt0, Wt1, Wt2);
  proj_kernel<<<dim3(32, 8, 4), 256, 0, stream>>>(
      Xt0, Xt1, Xt2, bq, bk, bv, Wt0, Wt1, Wt2, qh, kh, khT, vhT, mask, maskp);
  attn_kernel<<<dim3(32, 16), 512, 0, stream>>>(qh, kh, khT, vhT, maskp,
                                                out, out + (size_t)B_ * LQ_ * DM_);
}

// Round 7
// 257.536 us; speedup vs baseline: 1.0703x; 1.0242x over previous
//
#include <hip/hip_runtime.h>
#include <hip/hip_bf16.h>
#include <stdint.h>

typedef __bf16 bf16x8 __attribute__((ext_vector_type(8)));
typedef __bf16 bf16x4 __attribute__((ext_vector_type(4)));
typedef float f32x4 __attribute__((ext_vector_type(4)));

#define B_ 2
#define LQ_ 2048
#define LK_ 2048
#define NH_ 16
#define DH_ 64
#define DM_ 1024
#define NKT_ (LK_ / 64)

#define AS1 __attribute__((address_space(1)))
#define AS3 __attribute__((address_space(3)))

__device__ __forceinline__ void gload_lds16(const void* g, void* l) {
  __builtin_amdgcn_global_load_lds((const AS1 uint32_t*)g, (AS3 uint32_t*)l, 16, 0, 0);
}

// Fused prep (R12 = R9 arrangement): blocks [0,960) convert q,k,v,Wq,Wk,Wv
// fp32 -> bf16 k-tiled T[kt][row][32] (chunk c' stores true chunk c'^(row&3));
// blocks [960,9152) pack the mask to bits. (R11's mask-in-proj z-slice ran as
// a serial tail after the GEMM blocks and cost ~6us — reverted.)
__global__ __launch_bounds__(256) void prep_kernel(
    const float* __restrict__ q, const float* __restrict__ k,
    const float* __restrict__ v, const float* __restrict__ wq,
    const float* __restrict__ wk, const float* __restrict__ wv,
    const int* __restrict__ mask,
    __bf16* __restrict__ Xt0, __bf16* __restrict__ Xt1, __bf16* __restrict__ Xt2,
    __bf16* __restrict__ Wt0, __bf16* __restrict__ Wt1, __bf16* __restrict__ Wt2,
    unsigned* __restrict__ maskp) {
  const int t = threadIdx.x;
  const int bidx = blockIdx.x;
  if (bidx >= 960) {
    // ---- mask pack: thread covers 4 ints; nibble OR-reduce over 8 lanes ----
    int pb = bidx - 960;
    int lane = t & 63;
    size_t gi = ((size_t)pb * 256 + t) * 4;
    int4 mv = *(const int4*)(mask + gi);
    unsigned nib = (mv.x != 0 ? 1u : 0u) | (mv.y != 0 ? 2u : 0u) |
                   (mv.z != 0 ? 4u : 0u) | (mv.w != 0 ? 8u : 0u);
    unsigned vv = nib << ((lane & 7) * 4);
    vv |= __shfl_xor(vv, 1, 64);
    vv |= __shfl_xor(vv, 2, 64);
    vv |= __shfl_xor(vv, 4, 64);
    if ((lane & 7) == 0) maskp[gi >> 5] = vv;
    return;
  }
  // ---- cvt: 16 source rows x 1024 k through LDS transpose ----
  __shared__ __align__(16) __bf16 lb[16][1032];
  const float* src; __bf16* dst; int rows, m0;
  if (bidx < 256)      { src = q;  dst = Xt0; rows = 4096; m0 = bidx * 16; }
  else if (bidx < 512) { src = k;  dst = Xt1; rows = 4096; m0 = (bidx - 256) * 16; }
  else if (bidx < 768) { src = v;  dst = Xt2; rows = 4096; m0 = (bidx - 512) * 16; }
  else if (bidx < 832) { src = wq; dst = Wt0; rows = 1024; m0 = (bidx - 768) * 16; }
  else if (bidx < 896) { src = wk; dst = Wt1; rows = 1024; m0 = (bidx - 832) * 16; }
  else                 { src = wv; dst = Wt2; rows = 1024; m0 = (bidx - 896) * 16; }
#pragma unroll
  for (int i = 0; i < 16; i++) {
    float4 f = *(const float4*)(src + (size_t)(m0 + i) * DM_ + t * 4);
    bf16x4 o;
    o[0] = (__bf16)f.x; o[1] = (__bf16)f.y; o[2] = (__bf16)f.z; o[3] = (__bf16)f.w;
    *(bf16x4*)&lb[i][t * 4] = o;
  }
  __syncthreads();
  const int wave = t >> 6, lane = t & 63;
  const int m = lane >> 2, c = lane & 3;
#pragma unroll
  for (int j = 0; j < 8; j++) {
    int kt = wave * 8 + j;
    bf16x8 val = *(const bf16x8*)&lb[m][kt * 32 + (c ^ (m & 3)) * 8];
    *(bf16x8*)(dst + ((size_t)kt * rows + m0 + m) * 32 + c * 8) = val;  // 1KB/instr
  }
}

// GEMM C = X @ W^T + bias, 128x128 tile, BK=32, double-buffered staging from
// k-tiled inputs: each global_load_lds covers one contiguous 1KB span.
// mode=blockIdx.z: 0=q(std), 1=k(std+T), 2=v(T). T out: T[bh][kti][d][64].
// mode-0 (qh) output pre-scaled by log2e/8 so attn's exp2 needs no mul.
__global__ __launch_bounds__(256) void proj_kernel(
    const __bf16* __restrict__ Xt0, const __bf16* __restrict__ Xt1,
    const __bf16* __restrict__ Xt2,
    const float* __restrict__ b0p, const float* __restrict__ b1p,
    const float* __restrict__ b2p,
    const __bf16* __restrict__ Wt0, const __bf16* __restrict__ Wt1,
    const __bf16* __restrict__ Wt2,
    __bf16* __restrict__ qh, __bf16* __restrict__ kh,
    __bf16* __restrict__ khT, __bf16* __restrict__ vhT) {
  __shared__ __align__(16) __bf16 smem[2][2][128 * 32];
  __bf16* cbuf = &smem[0][0][0];  // epilogue alias (18 KB < 32 KB)

  const int mode = blockIdx.z;
  const __bf16* Xt = mode == 0 ? Xt0 : (mode == 1 ? Xt1 : Xt2);
  const __bf16* Wt = mode == 0 ? Wt0 : (mode == 1 ? Wt1 : Wt2);
  const float* bias = mode == 0 ? b0p : (mode == 1 ? b1p : b2p);
  __bf16* ostd = mode == 0 ? qh : (mode == 1 ? kh : nullptr);
  __bf16* otr = mode == 0 ? nullptr : (mode == 1 ? khT : vhT);
  const float osc = mode == 0 ? 0.18033688f : 1.0f;  // log2(e)/8 folded into Q

  const int t = threadIdx.x;
  const int wave = t >> 6, lane = t & 63;
  const int lo16 = lane & 15, quad = lane >> 4;
  const int wm = wave >> 1, wn = wave & 1;
  const int m0 = blockIdx.x * 128, n0 = blockIdx.y * 128;

  f32x4 acc[4][4] = {};

  auto stage = [&](int kt, int sel) {
#pragma unroll
    for (int ii = 2 * wave; ii < 2 * wave + 2; ii++) {
      gload_lds16(Xt + ((size_t)kt * 4096 + m0 + ii * 16) * 32 + lane * 8,
                  &smem[sel][0][ii * 512]);
      gload_lds16(Wt + ((size_t)kt * 1024 + n0 + ii * 16) * 32 + lane * 8,
                  &smem[sel][1][ii * 512]);
    }
  };

  stage(0, 0);
  for (int kt = 0; kt < 32; kt++) {
    const int sel = kt & 1;
    __syncthreads();
    if (kt + 1 < 32) stage(kt + 1, sel ^ 1);
    bf16x8 af[4], bfr[4];
#pragma unroll
    for (int g = 0; g < 4; g++) {
      int ar = wm * 64 + g * 16 + lo16;
      af[g] = *(const bf16x8*)(&smem[sel][0][ar * 32 + (quad ^ (ar & 3)) * 8]);
      int br = wn * 64 + g * 16 + lo16;
      bfr[g] = *(const bf16x8*)(&smem[sel][1][br * 32 + (quad ^ (br & 3)) * 8]);
    }
#pragma unroll
    for (int gm = 0; gm < 4; gm++)
#pragma unroll
      for (int gn = 0; gn < 4; gn++)
        acc[gm][gn] =
            __builtin_amdgcn_mfma_f32_16x16x32_bf16(af[gm], bfr[gn], acc[gm][gn], 0, 0, 0);
  }

  const int b = m0 >> 11, l0 = m0 & 2047;
  for (int nhf = 0; nhf < 2; nhf++) {
    int h = (n0 >> 6) + nhf;
    int bh = b * NH_ + h;
    if (ostd) {
      __syncthreads();
      if (wn == nhf) {
#pragma unroll
        for (int gn = 0; gn < 4; gn++) {
          float bi = bias[n0 + nhf * 64 + gn * 16 + lo16];
#pragma unroll
          for (int gm = 0; gm < 4; gm++)
#pragma unroll
            for (int r = 0; r < 4; r++)
              cbuf[(wm * 64 + gm * 16 + quad * 4 + r) * 72 + gn * 16 + lo16] =
                  (__bf16)((acc[gm][gn][r] + bi) * osc);
        }
      }
      __syncthreads();
      int m = t >> 1, coff = (t & 1) * 32;
      __bf16* dst = ostd + ((size_t)bh * LQ_ + l0 + m) * DH_ + coff;
#pragma unroll
      for (int j = 0; j < 4; j++)
        *(bf16x8*)(dst + j * 8) = *(const bf16x8*)&cbuf[m * 72 + coff + j * 8];
    }
    if (otr) {
      __syncthreads();
      if (wn == nhf) {
#pragma unroll
        for (int gn = 0; gn < 4; gn++) {
          float bi = bias[n0 + nhf * 64 + gn * 16 + lo16];
#pragma unroll
          for (int gm = 0; gm < 4; gm++) {
            bf16x4 pk;
#pragma unroll
            for (int r = 0; r < 4; r++) pk[r] = (__bf16)(acc[gm][gn][r] + bi);
            *(bf16x4*)&cbuf[(gn * 16 + lo16) * 136 + wm * 64 + gm * 16 + quad * 4] = pk;
          }
        }
      }
      __syncthreads();
      int d = t >> 2, mc = (t & 3) * 32;
      int kti = (l0 + mc) >> 6, kl = (l0 + mc) & 63;
      __bf16* dst = otr + ((size_t)(bh * NKT_ + kti) * 64 + d) * 64 + kl;
#pragma unroll
      for (int j = 0; j < 4; j++)
        *(bf16x8*)(dst + j * 8) = *(const bf16x8*)&cbuf[d * 136 + mc + j * 8];
    }
  }
}

// Flash attention (R12): R11 + swapped QK^T. Computing mfma(K,Q) instead of
// mfma(Q,K) flips C to [row=k_local][col=q]: each lane then holds 4
// k-contiguous P values per gg -> P-store packs into 4x ds_write_b64 (was 16
// scalar b16 stores) and each lane needs only its own q-row's 2 mask words
// (was 8). A-frag registers are operand-role-symmetric so kb/a_q reads are
// unchanged; a_p reads and PV/PK/lsum MFMAs byte-identical to verified R11.
// 8 waves x 16 q-rows (512 thr), 2 blocks/CU; setprio around MFMA clusters;
// lsum via MFMA-with-ones; Q pre-scaled in proj -> bare exp2. LDS = 66 KB.
__global__ __launch_bounds__(512) void attn_kernel(
    const __bf16* __restrict__ qh, const __bf16* __restrict__ kh,
    const __bf16* __restrict__ khT, const __bf16* __restrict__ vhT,
    const unsigned* __restrict__ maskp,
    float* __restrict__ out_k, float* __restrict__ out_v) {
  __shared__ __align__(16) __bf16 kbuf[2][64 * 64];
  __shared__ __align__(16) __bf16 ktbuf[2][64 * 64];
  __shared__ __align__(16) __bf16 vtbuf[2][64 * 64];
  __shared__ __align__(16) __bf16 p_lds[8][16][72];  // per-wave P[q][k]

  const int t = threadIdx.x;
  const int wave = t >> 6, lane = t & 63;
  const int lo16 = lane & 15, quad = lane >> 4;
  const int bh = blockIdx.x;
  const int b = bh >> 4, h = bh & 15;
  const int q0 = blockIdx.y * 128 + wave * 16;
  const int srow = lane >> 3;
  const int scg = (lane & 7) ^ srow;  // XOR chunk swizzle (store side)
  const int rsw = lo16 & 7;           // read-side row & 7

  bf16x8 a_q0, a_q1;
  {
    const __bf16* qrow = qh + ((size_t)bh * LQ_ + q0 + lo16) * DH_ + quad * 8;
    a_q0 = *(const bf16x8*)(qrow);
    a_q1 = *(const bf16x8*)(qrow + 32);
  }

  bf16x8 ones;
#pragma unroll
  for (int j = 0; j < 8; j++) ones[j] = (__bf16)1.0f;

  f32x4 acc_v[4] = {};
  f32x4 acc_k[4] = {};
  f32x4 acc_l = {};

  const __bf16* khb = kh + (size_t)bh * LK_ * DH_;
  const __bf16* ktb = khT + (size_t)bh * LK_ * DH_;
  const __bf16* vtb = vhT + (size_t)bh * LK_ * DH_;

  const int row_s = wave * 8 + srow;
  auto stage = [&](int kti, int sel) {
    const int tb = kti * 4096;
    gload_lds16(khb + (size_t)(kti * 64 + row_s) * DH_ + scg * 8, &kbuf[sel][wave * 512]);
    gload_lds16(ktb + tb + row_s * 64 + scg * 8, &ktbuf[sel][wave * 512]);
    gload_lds16(vtb + tb + row_s * 64 + scg * 8, &vtbuf[sel][wave * 512]);
  };

  stage(0, 0);
  for (int kti = 0; kti < NKT_; kti++) {
    const int cur = kti & 1;
    __syncthreads();  // drains stage(cur), issued a full compute-phase ago
    if (kti + 1 < NKT_) stage(kti + 1, cur ^ 1);

    // this lane's q-row mask words (2 per tile; was 8) — early issue
    const unsigned* mb =
        maskp + ((size_t)b * LQ_ + q0 + lo16) * (LK_ / 32) + kti * 2;
    unsigned mw0 = mb[0], mw1 = mb[1];

    // ---- S^T = K Q^T (swapped operands; same registers, same reads) ----
    __builtin_amdgcn_s_setprio(1);
    f32x4 s[4];
#pragma unroll
    for (int gg = 0; gg < 4; gg++) {
      int row = gg * 16 + lo16;
      bf16x8 kb0 = *(const bf16x8*)(&kbuf[cur][row * 64 + ((quad ^ rsw) * 8)]);
      bf16x8 kb1 = *(const bf16x8*)(&kbuf[cur][row * 64 + (((quad + 4) ^ rsw) * 8)]);
      f32x4 z = {};
      z = __builtin_amdgcn_mfma_f32_16x16x32_bf16(kb0, a_q0, z, 0, 0, 0);
      z = __builtin_amdgcn_mfma_f32_16x16x32_bf16(kb1, a_q1, z, 0, 0, 0);
      s[gg] = z;  // C[row=k_local=quad*4+r][col=q=lo16]; k = gg*16+quad*4+r
    }
    __builtin_amdgcn_s_setprio(0);

    // ---- mask + exp2 (Q pre-scaled; fixed max) + packed P store ----
#pragma unroll
    for (int gg = 0; gg < 4; gg++) {
      unsigned w = (gg >= 2) ? mw1 : mw0;
      bf16x4 pk;
#pragma unroll
      for (int r = 0; r < 4; r++) {
        int bitpos = (gg & 1) * 16 + quad * 4 + r;
        float pe = __builtin_amdgcn_exp2f(s[gg][r]);
        pk[r] = ((w >> bitpos) & 1) ? (__bf16)pe : (__bf16)0.0f;
      }
      *(bf16x4*)&p_lds[wave][lo16][gg * 16 + quad * 4] = pk;  // k-contiguous
    }
    bf16x8 a_p0 = *(const bf16x8*)&p_lds[wave][lo16][quad * 8];
    bf16x8 a_p1 = *(const bf16x8*)&p_lds[wave][lo16][32 + quad * 8];

    // ---- O_v += P V, O_k += P K, lsum += P 1 ----
    __builtin_amdgcn_s_setprio(1);
#pragma unroll
    for (int gg = 0; gg < 4; gg++) {
      int row = gg * 16 + lo16;
      bf16x8 bv0 = *(const bf16x8*)(&vtbuf[cur][row * 64 + ((quad ^ rsw) * 8)]);
      bf16x8 bv1 = *(const bf16x8*)(&vtbuf[cur][row * 64 + (((quad + 4) ^ rsw) * 8)]);
      bf16x8 bk0 = *(const bf16x8*)(&ktbuf[cur][row * 64 + ((quad ^ rsw) * 8)]);
      bf16x8 bk1 = *(const bf16x8*)(&ktbuf[cur][row * 64 + (((quad + 4) ^ rsw) * 8)]);
      acc_v[gg] = __builtin_amdgcn_mfma_f32_16x16x32_bf16(a_p0, bv0, acc_v[gg], 0, 0, 0);
      acc_v[gg] = __builtin_amdgcn_mfma_f32_16x16x32_bf16(a_p1, bv1, acc_v[gg], 0, 0, 0);
      acc_k[gg] = __builtin_amdgcn_mfma_f32_16x16x32_bf16(a_p0, bk0, acc_k[gg], 0, 0, 0);
      acc_k[gg] = __builtin_amdgcn_mfma_f32_16x16x32_bf16(a_p1, bk1, acc_k[gg], 0, 0, 0);
    }
    acc_l = __builtin_amdgcn_mfma_f32_16x16x32_bf16(a_p0, ones, acc_l, 0, 0, 0);
    acc_l = __builtin_amdgcn_mfma_f32_16x16x32_bf16(a_p1, ones, acc_l, 0, 0, 0);
    __builtin_amdgcn_s_setprio(0);
  }

  // acc_l: every column equals the row-sum -> per-reg reciprocal, no shuffle
  float inv_l[4];
#pragma unroll
  for (int r = 0; r < 4; r++) inv_l[r] = 1.0f / acc_l[r];
  size_t obase = ((size_t)b * LQ_ + q0 + quad * 4) * DM_ + h * DH_;
#pragma unroll
  for (int gg = 0; gg < 4; gg++) {
#pragma unroll
    for (int r = 0; r < 4; r++) {
      size_t idx = obase + (size_t)r * DM_ + gg * 16 + lo16;
      out_k[idx] = acc_k[gg][r] * inv_l[r];
      out_v[idx] = acc_v[gg][r] * inv_l[r];
    }
  }
}

extern "C" void kernel_launch(void* const* d_in, const int* in_sizes, int n_in,
                              void* d_out, int out_size, void* d_ws, size_t ws_size,
                              hipStream_t stream) {
  const float* q = (const float*)d_in[0];
  const float* k = (const float*)d_in[1];
  const float* v = (const float*)d_in[2];
  const int* mask = (const int*)d_in[3];
  const float* Wq = (const float*)d_in[4];
  const float* bq = (const float*)d_in[5];
  const float* Wk = (const float*)d_in[6];
  const float* bk = (const float*)d_in[7];
  const float* Wv = (const float*)d_in[8];
  const float* bv = (const float*)d_in[9];
  float* out = (float*)d_out;

  // ws: qh | kh | khT | vhT (bf16, 8.4MB ea) | maskp (1MB) | [scratch if fits]
  const size_t HTOT = (size_t)B_ * NH_ * LQ_ * DH_;
  const size_t XTOT = (size_t)B_ * LQ_ * DM_;
  const size_t MASKW = (size_t)B_ * LQ_ * (LK_ / 32);
  __bf16* qh = (__bf16*)d_ws;
  __bf16* kh = qh + HTOT;
  __bf16* khT = kh + HTOT;
  __bf16* vhT = khT + HTOT;
  unsigned* maskp = (unsigned*)(vhT + HTOT);

  // k-tiled bf16 X/W scratch (31.5 MB): prefer tail of d_ws; fall back to
  // d_out (dead until attn writes outputs) when ws is too small.
  const size_t SCR_ELEMS = 3 * XTOT + 3 * (size_t)DM_ * DM_;
  const size_t NEED = 4 * HTOT * sizeof(__bf16) + MASKW * sizeof(unsigned) +
                      SCR_ELEMS * sizeof(__bf16);
  __bf16* scr = (ws_size >= NEED) ? (__bf16*)(maskp + MASKW) : (__bf16*)d_out;
  __bf16* Xt0 = scr;
  __bf16* Xt1 = Xt0 + XTOT;
  __bf16* Xt2 = Xt1 + XTOT;
  __bf16* Wt0 = Xt2 + XTOT;
  __bf16* Wt1 = Wt0 + (size_t)DM_ * DM_;
  __bf16* Wt2 = Wt1 + (size_t)DM_ * DM_;

  prep_kernel<<<960 + 8192, 256, 0, stream>>>(
      q, k, v, Wq, Wk, Wv, mask, Xt0, Xt1, Xt2, Wt0, Wt1, Wt2, maskp);
  proj_kernel<<<dim3(32, 8, 3), 256, 0, stream>>>(
      Xt0, Xt1, Xt2, bq, bk, bv, Wt0, Wt1, Wt2, qh, kh, khT, vhT);
  attn_kernel<<<dim3(32, 16), 512, 0, stream>>>(qh, kh, khT, vhT, maskp,
                                                out, out + (size_t)B_ * LQ_ * DM_);
}